// Round 1
// baseline (94.045 us; speedup 1.0000x reference)
//
#include <hip/hip_runtime.h>

// Problem constants (from reference): B=32, L=4096, D=128, N=5, V=128
constexpr int Bn = 32;
constexpr int Ln = 4096;
constexpr int Dn = 128;
constexpr int Vn = 128;
constexpr int N1 = 4;  // N - 1 context slots

// Kernel A: build T[k][t][v] = dot(emb[t], W[v, k*D : (k+1)*D])
// grid: 4*128 = 512 blocks (one per (k,t)), block: 128 threads (one per v)
__global__ void build_table_kernel(const float* __restrict__ emb,
                                   const float* __restrict__ W,
                                   float* __restrict__ T) {
    const int kt = blockIdx.x;        // k*128 + t
    const int k  = kt >> 7;
    const int t  = kt & 127;
    const int v  = threadIdx.x;       // 0..127

    __shared__ float4 e[Dn / 4];
    if (threadIdx.x < Dn / 4) {
        e[threadIdx.x] = ((const float4*)(emb + t * Dn))[threadIdx.x];
    }
    __syncthreads();

    const float4* w = (const float4*)(W + (size_t)v * (Dn * N1) + k * Dn);
    float acc = 0.f;
#pragma unroll
    for (int i = 0; i < Dn / 4; ++i) {
        float4 wv = w[i];
        float4 ev = e[i];
        acc += wv.x * ev.x + wv.y * ev.y + wv.z * ev.z + wv.w * ev.w;
    }
    T[(size_t)kt * Vn + v] = acc;
}

// Kernel B: out[b,j,v] = bias[v] + sum_k T[k][x[b,j-4+k]][v]   (j>=4; else bias[v])
// One thread per float4 of v: B*L*(V/4) = 4,194,304 threads.
__global__ void ngram_logits_kernel(const int* __restrict__ x,
                                    const float* __restrict__ T,
                                    const float* __restrict__ bias,
                                    float* __restrict__ out) {
    const int tid = blockIdx.x * blockDim.x + threadIdx.x;
    const int vq  = tid & 31;        // v / 4
    const int pos = tid >> 5;        // b*L + j
    const int j   = pos & (Ln - 1);  // L is a power of two

    float4 acc = ((const float4*)bias)[vq];

    if (j >= N1) {
        const int* xp = x + (pos - N1);  // same batch row since j >= 4
        const int t0 = xp[0];
        const int t1 = xp[1];
        const int t2 = xp[2];
        const int t3 = xp[3];
        const float4* Tq = (const float4*)T;  // T viewed as [4][128][32] float4
        const float4 a0 = Tq[(size_t)(0 * Vn + t0) * 32 + vq];
        const float4 a1 = Tq[(size_t)(1 * Vn + t1) * 32 + vq];
        const float4 a2 = Tq[(size_t)(2 * Vn + t2) * 32 + vq];
        const float4 a3 = Tq[(size_t)(3 * Vn + t3) * 32 + vq];
        acc.x += a0.x + a1.x + a2.x + a3.x;
        acc.y += a0.y + a1.y + a2.y + a3.y;
        acc.z += a0.z + a1.z + a2.z + a3.z;
        acc.w += a0.w + a1.w + a2.w + a3.w;
    }

    ((float4*)out)[(size_t)pos * 32 + vq] = acc;
}

extern "C" void kernel_launch(void* const* d_in, const int* in_sizes, int n_in,
                              void* d_out, int out_size, void* d_ws, size_t ws_size,
                              hipStream_t stream) {
    const int*   x    = (const int*)d_in[0];    // (B, L) int32
    const float* emb  = (const float*)d_in[1];  // (V, D) fp32
    const float* W    = (const float*)d_in[2];  // (V, D*(N-1)) fp32
    const float* bias = (const float*)d_in[3];  // (V,) fp32
    float*       out  = (float*)d_out;          // (B, L, V) fp32
    float*       T    = (float*)d_ws;           // (4, 128, 128) fp32 = 256 KiB

    // Kernel A: precompute the (k, token, v) logit table.
    build_table_kernel<<<N1 * Vn, Vn, 0, stream>>>(emb, W, T);

    // Kernel B: stream the output.
    const int total_threads = Bn * Ln * (Vn / 4);  // 4,194,304
    const int block = 256;
    ngram_logits_kernel<<<total_threads / block, block, 0, stream>>>(x, T, bias, out);
}

// Round 3
// 92.724 us; speedup vs baseline: 1.0142x; 1.0142x over previous
//
#include <hip/hip_runtime.h>

// Problem constants (from reference): B=32, L=4096, D=128, N=5, V=128
constexpr int Bn = 32;
constexpr int Ln = 4096;
constexpr int Dn = 128;
constexpr int Vn = 128;
constexpr int N1 = 4;  // N - 1 context slots

typedef float vfloat4 __attribute__((ext_vector_type(4)));  // native vec for nontemporal builtins

// Kernel A: build T[k][t][v] = dot(emb[t], W[v, k*D : (k+1)*D]) (+ bias[v] for k==0)
// grid: 4*128 = 512 blocks (one per (k,t)), block: 128 threads (one per v)
__global__ void build_table_kernel(const float* __restrict__ emb,
                                   const float* __restrict__ W,
                                   const float* __restrict__ bias,
                                   float* __restrict__ T) {
    const int kt = blockIdx.x;        // k*128 + t
    const int k  = kt >> 7;
    const int t  = kt & 127;
    const int v  = threadIdx.x;       // 0..127

    __shared__ float4 e[Dn / 4];
    if (threadIdx.x < Dn / 4) {
        e[threadIdx.x] = ((const float4*)(emb + t * Dn))[threadIdx.x];
    }
    __syncthreads();

    const float4* w = (const float4*)(W + (size_t)v * (Dn * N1) + k * Dn);
    float acc = (k == 0) ? bias[v] : 0.f;  // fold bias into slot-0 table
#pragma unroll
    for (int i = 0; i < Dn / 4; ++i) {
        float4 wv = w[i];
        float4 ev = e[i];
        acc += wv.x * ev.x + wv.y * ev.y + wv.z * ev.z + wv.w * ev.w;
    }
    T[(size_t)kt * Vn + v] = acc;
}

// Kernel B: out[b,j,v] = sum_k T'[k][x[b,j-4+k]][v]  (bias folded into T'[0]);
// j<4 rows are bias-only. Each thread computes 4 consecutive positions x one
// float4 of v. Threads: B*L/4 * (V/4) = 1,048,576.
__global__ void __launch_bounds__(256)
ngram_logits_kernel(const int* __restrict__ x,
                    const float* __restrict__ T,
                    const float* __restrict__ bias,
                    float* __restrict__ out) {
    const int tid     = blockIdx.x * blockDim.x + threadIdx.x;
    const int vq      = tid & 31;          // v / 4
    const int g       = tid >> 5;          // position group
    const int basepos = g << 2;            // first of 4 positions (4-aligned)
    const int j0      = basepos & (Ln - 1);

    vfloat4* outq = (vfloat4*)out;

    if (j0 == 0) {
        // positions j=0..3: bias-only rows
        const vfloat4 bv = ((const vfloat4*)bias)[vq];
#pragma unroll
        for (int i = 0; i < 4; ++i)
            __builtin_nontemporal_store(bv, &outq[(size_t)(basepos + i) * 32 + vq]);
        return;
    }

    // token window w[0..6] = x[basepos-4 .. basepos+2]; both int4 loads 16B-aligned
    const int4 xa = *(const int4*)(x + basepos - 4);
    const int4 xb = *(const int4*)(x + basepos);
    int w[7] = {xa.x, xa.y, xa.z, xa.w, xb.x, xb.y, xb.z};

    const vfloat4* Tq = (const vfloat4*)T;  // [4][128][32] vfloat4
    vfloat4 acc[4];
#pragma unroll
    for (int i = 0; i < 4; ++i) {
        vfloat4 a = Tq[(size_t)(0 * Vn + w[i + 0]) * 32 + vq];
#pragma unroll
        for (int k = 1; k < N1; ++k) {
            a += Tq[(size_t)(k * Vn + w[i + k]) * 32 + vq];
        }
        acc[i] = a;
    }

#pragma unroll
    for (int i = 0; i < 4; ++i)
        __builtin_nontemporal_store(acc[i], &outq[(size_t)(basepos + i) * 32 + vq]);
}

extern "C" void kernel_launch(void* const* d_in, const int* in_sizes, int n_in,
                              void* d_out, int out_size, void* d_ws, size_t ws_size,
                              hipStream_t stream) {
    const int*   x    = (const int*)d_in[0];    // (B, L) int32
    const float* emb  = (const float*)d_in[1];  // (V, D) fp32
    const float* W    = (const float*)d_in[2];  // (V, D*(N-1)) fp32
    const float* bias = (const float*)d_in[3];  // (V,) fp32
    float*       out  = (float*)d_out;          // (B, L, V) fp32
    float*       T    = (float*)d_ws;           // (4, 128, 128) fp32 = 256 KiB

    build_table_kernel<<<N1 * Vn, Vn, 0, stream>>>(emb, W, bias, T);

    const int total_threads = (Bn * Ln / 4) * (Vn / 4);  // 1,048,576
    const int block = 256;
    ngram_logits_kernel<<<total_threads / block, block, 0, stream>>>(x, T, bias, out);
}